// Round 15
// baseline (207.184 us; speedup 1.0000x reference)
//
#include <hip/hip_runtime.h>
#include <hip/hip_bf16.h>
#include <math.h>

#define SEQ 2048
#define DM 1024
#define NH 16
#define HD 64
#define NBH 32      // B*NH
#define MTOT 4096   // B*SEQ

typedef __attribute__((ext_vector_type(8))) short short8;
typedef __attribute__((ext_vector_type(4))) float floatx4;
typedef __attribute__((ext_vector_type(8))) unsigned short u16x8;
typedef __attribute__((ext_vector_type(4))) unsigned short u16x4;

__device__ __forceinline__ unsigned short f2bf(float f) {
    unsigned int u = __float_as_uint(f);
    u += 0x7FFFu + ((u >> 16) & 1u);    // round-to-nearest-even
    return (unsigned short)(u >> 16);
}
__device__ __forceinline__ float bf2f(unsigned short h) {
    unsigned int u = (unsigned int)h << 16;
    return __uint_as_float(u);
}

#define AS1C const __attribute__((address_space(1))) void*
#define AS3  __attribute__((address_space(3))) void*

// 0.125 * log2(e): folds the 1/sqrt(64) score scale AND the exp->exp2
// conversion into Q's projection epilogue.
#define QSCALE 0.18033688011112042f

// ---------------------------------------------------------------------------
// Merged conversion kernel:
//  blocks [0,2048):    x fp32 [4096][1024] -> bf16 xb (8 elems/thread)
//  blocks [2048,3072): W fp32 [K][N] -> Wt bf16 [N][K], 64x64 tiles, 4 Ws
// ---------------------------------------------------------------------------
__global__ __launch_bounds__(256) void cvt_xw_kernel(
    const float* __restrict__ x, unsigned short* __restrict__ xb,
    const float* __restrict__ Wq, const float* __restrict__ Wk,
    const float* __restrict__ Wv, const float* __restrict__ Wo,
    unsigned short* __restrict__ Wt)
{
    if (blockIdx.x < 2048) {
        size_t base = ((size_t)blockIdx.x * 256 + threadIdx.x) * 8;
        float4 a = *(const float4*)(x + base);
        float4 b = *(const float4*)(x + base + 4);
        u16x8 o;
        o[0]=f2bf(a.x); o[1]=f2bf(a.y); o[2]=f2bf(a.z); o[3]=f2bf(a.w);
        o[4]=f2bf(b.x); o[5]=f2bf(b.y); o[6]=f2bf(b.z); o[7]=f2bf(b.w);
        *(u16x8*)(xb + base) = o;
        return;
    }
    __shared__ float Ls[64][65];
    const int bid = blockIdx.x - 2048;
    const int z = bid >> 8;
    const float* src = (z==0) ? Wq : (z==1) ? Wk : (z==2) ? Wv : Wo;
    unsigned short* dst = Wt + (size_t)z * DM * DM;
    const int tid = threadIdx.x;
    const int k0 = (bid & 15) * 64, n0 = ((bid >> 4) & 15) * 64;

    int r = tid >> 2, cseg = (tid & 3) * 16;
    #pragma unroll
    for (int e = 0; e < 4; ++e) {
        float4 v = *(const float4*)(src + (size_t)(k0 + r) * DM + n0 + cseg + e*4);
        Ls[r][cseg+e*4+0] = v.x; Ls[r][cseg+e*4+1] = v.y;
        Ls[r][cseg+e*4+2] = v.z; Ls[r][cseg+e*4+3] = v.w;
    }
    __syncthreads();
    int n = tid >> 2, kseg = (tid & 3) * 16;
    #pragma unroll
    for (int half = 0; half < 2; ++half) {
        u16x8 o;
        #pragma unroll
        for (int e = 0; e < 8; ++e) o[e] = f2bf(Ls[kseg + half*8 + e][n]);
        *(u16x8*)(dst + (size_t)(n0 + n) * DM + k0 + kseg + half*8) = o;
    }
}

// ---------------------------------------------------------------------------
// bf16 MFMA GEMM core (m97 structure) + r9-style XOR-granule swizzle.
// Old layout: frag reads at row*64B + quad*16B -> row stride 16 dwords ==
// 16 (mod 32) -> a 16-lane quarter-wave hit only 2 bank-groups = 8-WAY
// conflict on EVERY A/B frag read (m136: 2.94x per read). Fix (proven in
// the attention kernel since r9): stage with source granule XOR'd by
// (row>>2)&3 (lane-only: scol = ((lane&3)^((lane>>4)&3))*8; all row terms
// are ==0 mod 4) and read frags at fsw = (quad^((l16>>2)&3))*8 ->
// 8 positions x 2 lanes = free 2-way.
// ---------------------------------------------------------------------------
#define GEMM_CORE(A_, Bt_, m0_, n0_)                                          \
    const int tid = threadIdx.x;                                              \
    const int wave = tid >> 6, lane = tid & 63;                               \
    const int quad = lane >> 4, l16 = lane & 15;                              \
    const int mh = (wave & 1) * 64, nh = (wave >> 1) * 64;                    \
    const int fsw = (quad ^ ((l16 >> 2) & 3)) * 8;                            \
    floatx4 acc[4][4];                                                        \
    _Pragma("unroll")                                                         \
    for (int i = 0; i < 4; ++i)                                               \
        _Pragma("unroll")                                                     \
        for (int j = 0; j < 4; ++j) acc[i][j] = (floatx4){0.f,0.f,0.f,0.f};   \
    {                                                                         \
        const int srow = wave*32 + (lane>>2);                                 \
        const int scol = ((lane & 3) ^ ((lane >> 4) & 3)) * 8;                \
        const unsigned short* ga = A_ + (size_t)(m0_ + srow)*DM + scol;       \
        const unsigned short* gb = Bt_ + (size_t)(n0_ + srow)*DM + scol;      \
        char* lA = (char*)As; char* lB = (char*)Bs;                           \
        for (int k0 = 0; k0 < DM; k0 += 32) {                                 \
            __syncthreads();                                                  \
            _Pragma("unroll")                                                 \
            for (int u = 0; u < 2; ++u) {                                     \
                __builtin_amdgcn_global_load_lds(                             \
                    (AS1C)(ga + (size_t)u*16*DM + k0),                        \
                    (AS3)(lA + (wave*32 + u*16)*64), 16, 0, 0);               \
                __builtin_amdgcn_global_load_lds(                             \
                    (AS1C)(gb + (size_t)u*16*DM + k0),                        \
                    (AS3)(lB + (wave*32 + u*16)*64), 16, 0, 0);               \
            }                                                                 \
            __syncthreads();                                                  \
            short8 af[4], bf[4];                                              \
            _Pragma("unroll")                                                 \
            for (int t = 0; t < 4; ++t) {                                     \
                af[t] = *(const short8*)&As[(mh + t*16 + l16)*32 + fsw];      \
                bf[t] = *(const short8*)&Bs[(nh + t*16 + l16)*32 + fsw];      \
            }                                                                 \
            _Pragma("unroll")                                                 \
            for (int mt = 0; mt < 4; ++mt)                                    \
                _Pragma("unroll")                                             \
                for (int nt = 0; nt < 4; ++nt)                                \
                    acc[mt][nt] = __builtin_amdgcn_mfma_f32_16x16x32_bf16(    \
                        af[mt], bf[nt], acc[mt][nt], 0, 0, 0);                \
        }                                                                     \
    }

// ---------------------------------------------------------------------------
// QKV projection GEMM (r9-proven + swizzle). grid (32, 8, 3): z=0
// q(rope+QSCALE), 1 k(rope), 2 v -> V^T to global, key axis slot-permuted
// per 32-key block (key 16t+4q+r at slot 8q+4t+r). Q/K in pi-permuted dh
// layout (pos 4*l16+p holds col p*16+l16; same perm on Q and K).
// ---------------------------------------------------------------------------
__global__ __launch_bounds__(256, 3) void qkv_gemm_kernel(
    const unsigned short* __restrict__ xb, const unsigned short* __restrict__ Wt,
    const float* __restrict__ bq, const float* __restrict__ bk,
    const float* __restrict__ bv,
    unsigned short* __restrict__ qb, unsigned short* __restrict__ kb,
    unsigned short* __restrict__ vtg)
{
    __shared__ unsigned short As[128*32];
    __shared__ unsigned short Bs[128*32];
    const int z = blockIdx.z;
    const unsigned short* Bt = Wt + (size_t)z * DM * DM;
    const float* bias = (z==0) ? bq : (z==1) ? bk : bv;
    const int m0 = blockIdx.x * 128, n0 = blockIdx.y * 128;

    GEMM_CORE(xb, Bt, m0, n0)

    float bb[4];
    #pragma unroll
    for (int nt = 0; nt < 4; ++nt) bb[nt] = bias[n0 + nh + nt*16 + l16];

    if (z == 2) {
        // V^T epilogue with slot permutation: 4 rounds of LDS transpose.
        unsigned short* Tw = (wave & 1) ? Bs : As;
        const int b = m0 >> 11;
        const int bufsel = tid >> 7, nl = tid & 127;
        const int ng = n0 + nl, hh = ng >> 6, dhh = ng & 63;
        unsigned short* vrow = vtg + ((size_t)((b*NH + hh)*HD + dhh))*SEQ;
        #pragma unroll
        for (int t = 0; t < 4; ++t) {
            __syncthreads();
            #pragma unroll
            for (int nt = 0; nt < 4; ++nt)
                #pragma unroll
                for (int r = 0; r < 4; ++r)
                    Tw[(nh + nt*16 + l16)*24 + quad*4 + r] =
                        f2bf(acc[t][nt][r] + bb[nt]);
            __syncthreads();
            const unsigned short* T2 = bufsel ? Bs : As;
            int sbase = (m0 & 2047) + bufsel*64 + t*16;   // 16-aligned
            int t32 = (sbase >> 4) & 1;
            int sb32 = sbase & ~31;
            #pragma unroll
            for (int gq = 0; gq < 4; ++gq) {
                u16x4 v4 = *(const u16x4*)&T2[nl*24 + gq*4];
                *(u16x4*)(vrow + sb32 + gq*8 + t32*4) = v4;
            }
        }
    } else {
        unsigned short* outh = (z==0) ? qb : kb;
        const float scl = (z == 0) ? QSCALE : 1.0f;
        const int h = (n0 + nh) >> 6;   // one head per n-half
        float inv0 = __expf(-(float)l16        * 0.28782313662425572f);
        float inv1 = __expf(-(float)(l16 + 16) * 0.28782313662425572f);
        #pragma unroll
        for (int mt = 0; mt < 4; ++mt)
            #pragma unroll
            for (int r = 0; r < 4; ++r) {
                int m = m0 + mh + mt*16 + quad*4 + r;
                int b = m >> 11, s = m & (SEQ-1);
                float s0, c0, s1, c1;
                __sincosf((float)s * inv0, &s0, &c0);
                __sincosf((float)s * inv1, &s1, &c1);
                float a0 = acc[mt][0][r] + bb[0];   // col l16
                float a1 = acc[mt][1][r] + bb[1];   // col l16+16
                float a2 = acc[mt][2][r] + bb[2];   // col l16+32
                float a3 = acc[mt][3][r] + bb[3];   // col l16+48
                u16x4 o;
                o[0] = f2bf((a0*c0 - a2*s0) * scl);
                o[1] = f2bf((a1*c1 - a3*s1) * scl);
                o[2] = f2bf((a2*c0 + a0*s0) * scl);
                o[3] = f2bf((a3*c1 + a1*s1) * scl);
                *(u16x4*)(outh + ((size_t)((b*NH + h)*SEQ + s))*HD + 4*l16) = o;
            }
    }
}

// ---------------------------------------------------------------------------
// Output GEMM v2 + swizzle: 64x128 tile, grid (64,8) = 2 blocks/CU.
// Wave w covers all 64 m x 32 n (n-offset w*32). acc 4x2. LDS 12 KB.
// ---------------------------------------------------------------------------
__global__ __launch_bounds__(256, 2) void out_gemm_kernel(
    const unsigned short* __restrict__ ctxb, const unsigned short* __restrict__ Wto,
    const float* __restrict__ bo, float* __restrict__ outf)
{
    __shared__ unsigned short As[64*32];    // 4 KB
    __shared__ unsigned short Bs[128*32];   // 8 KB
    const int tid = threadIdx.x;
    const int wave = tid >> 6, lane = tid & 63;
    const int quad = lane >> 4, l16 = lane & 15;
    const int m0 = blockIdx.x * 64, n0 = blockIdx.y * 128;
    const int nw = wave * 32;
    const int fsw = (quad ^ ((l16 >> 2) & 3)) * 8;

    floatx4 acc[4][2];
    #pragma unroll
    for (int i = 0; i < 4; ++i)
        #pragma unroll
        for (int j = 0; j < 2; ++j) acc[i][j] = (floatx4){0.f,0.f,0.f,0.f};

    const int srow = lane >> 2;
    const int scol = ((lane & 3) ^ ((lane >> 4) & 3)) * 8;
    const unsigned short* ga = ctxb + (size_t)(m0 + wave*16 + srow)*DM + scol;
    const unsigned short* gb = Wto + (size_t)(n0 + wave*16 + srow)*DM + scol;
    char* lA = (char*)As; char* lB = (char*)Bs;

    for (int k0 = 0; k0 < DM; k0 += 32) {
        __syncthreads();
        __builtin_amdgcn_global_load_lds((AS1C)(ga + k0),
                                         (AS3)(lA + wave*1024), 16, 0, 0);
        #pragma unroll
        for (int u = 0; u < 2; ++u)
            __builtin_amdgcn_global_load_lds((AS1C)(gb + (size_t)u*64*DM + k0),
                                             (AS3)(lB + u*4096 + wave*1024), 16, 0, 0);
        __syncthreads();
        short8 af[4], bf[2];
        #pragma unroll
        for (int t = 0; t < 4; ++t)
            af[t] = *(const short8*)&As[(t*16 + l16)*32 + fsw];
        #pragma unroll
        for (int t = 0; t < 2; ++t)
            bf[t] = *(const short8*)&Bs[(nw + t*16 + l16)*32 + fsw];
        #pragma unroll
        for (int mt = 0; mt < 4; ++mt)
            #pragma unroll
            for (int nt = 0; nt < 2; ++nt)
                acc[mt][nt] = __builtin_amdgcn_mfma_f32_16x16x32_bf16(
                    af[mt], bf[nt], acc[mt][nt], 0, 0, 0);
    }

    float bb[2];
    #pragma unroll
    for (int nt = 0; nt < 2; ++nt) bb[nt] = bo[n0 + nw + nt*16 + l16];
    #pragma unroll
    for (int mt = 0; mt < 4; ++mt)
        #pragma unroll
        for (int r = 0; r < 4; ++r) {
            int m = m0 + mt*16 + quad*4 + r;
            #pragma unroll
            for (int nt = 0; nt < 2; ++nt)
                outf[(size_t)m*DM + n0 + nw + nt*16 + l16] = acc[mt][nt][r] + bb[nt];
        }
}

// ---------------------------------------------------------------------------
// Flash attention v6 (r12/r14-proven, 58.8 us): split-K over 2 key halves,
// 256 thr / 4 waves, q-tile 128, S^T=K*Q^T keeps P in registers, no-max
// exp2 softmax, XCD-local bh, XOR-granule swizzle, clean pack path.
// Separate combine kernel (r13's fused-fence variant flushes L2 — never
// again on this chip).
// ---------------------------------------------------------------------------
__global__ __launch_bounds__(256, 2) void attn_mfma_kernel(
    const unsigned short* __restrict__ Q, const unsigned short* __restrict__ K,
    const unsigned short* __restrict__ Vtg,
    unsigned short* __restrict__ Opart, float* __restrict__ Lpart)
{
    __shared__ unsigned short Ks[2*128*32];   // 16 KB [d-half][key][32]
    __shared__ unsigned short Vt[4*64*32];    // 16 KB [key-group][d][32 slots]

    const int tid  = threadIdx.x;
    const int wave = tid >> 6, lane = tid & 63;
    const int quad = lane >> 4, l16 = lane & 15;
    const int bh   = blockIdx.x & 31;            // XCD-local
    const int qt   = (blockIdx.x >> 5) & 15;     // q-tile (128 rows)
    const int half = blockIdx.x >> 9;            // key half

    const unsigned short* Qb = Q + (size_t)bh * SEQ * HD;
    const unsigned short* Kb = K + (size_t)bh * SEQ * HD + (size_t)half*1024*HD;
    const unsigned short* Vb = Vtg + (size_t)bh * HD * SEQ + half*1024;

    // Q fragments in registers: qf[qg][s] = Q[q = wave*32+qg*16+l16][d s-half]
    short8 qf[2][2];
    #pragma unroll
    for (int qg = 0; qg < 2; ++qg) {
        const unsigned short* qrow =
            Qb + (size_t)(qt*128 + wave*32 + qg*16 + l16)*HD;
        qf[qg][0] = *(const short8*)(qrow + quad*8);
        qf[qg][1] = *(const short8*)(qrow + 32 + quad*8);
    }

    // DMA staging: waves 0-1 stage K (16KB), waves 2-3 stage V (16KB);
    // 8 issues x 16B/thread. Granule XOR on (row>>2)&3.
    const unsigned short* gsrc[8];
    char* ldst[8];
    int step;
    if (wave < 2) {
        #pragma unroll
        for (int u = 0; u < 8; ++u) {
            int G = u*128 + wave*64 + lane;      // granule 0..1023
            int gl = G & 3, key = (G >> 2) & 127, s = G >> 9;
            gsrc[u] = Kb + (size_t)key*HD + s*32 + (gl ^ ((key>>2)&3))*8;
            ldst[u] = (char*)Ks + G*16;
        }
        step = 128*HD;
    } else {
        #pragma unroll
        for (int u = 0; u < 8; ++u) {
            int G = u*128 + (wave-2)*64 + lane;
            int gl = G & 3, d = (G >> 2) & 63, g = G >> 8;
            gsrc[u] = Vb + (size_t)d*SEQ + g*32 + (gl ^ ((d>>2)&3))*8;
            ldst[u] = (char*)Vt + G*16;
        }
        step = 128;
    }

    float l_p[2] = {0.f, 0.f};
    floatx4 Oacc[2][4];
    #pragma unroll
    for (int qg = 0; qg < 2; ++qg)
        #pragma unroll
        for (int dt = 0; dt < 4; ++dt) Oacc[qg][dt] = (floatx4){0.f,0.f,0.f,0.f};

    const int swz = (quad ^ (l16 >> 2)) * 8;

    for (int kt = 0; kt < 8; ++kt) {
        __syncthreads();   // prev iter done reading Ks/Vt
        #pragma unroll
        for (int u = 0; u < 8; ++u)
            __builtin_amdgcn_global_load_lds((AS1C)gsrc[u], (AS3)ldst[u], 16, 0, 0);
        #pragma unroll
        for (int u = 0; u < 8; ++u) gsrc[u] += step;
        __syncthreads();   // DMA drained

        #pragma unroll
        for (int g = 0; g < 4; ++g) {            // 32-key groups
            // S^T = K @ Q^T for the group's two 16-key tiles
            floatx4 Sc[2][2];                    // [t][qg]
            #pragma unroll
            for (int t = 0; t < 2; ++t)
                #pragma unroll
                for (int qg = 0; qg < 2; ++qg) Sc[t][qg] = (floatx4){0.f,0.f,0.f,0.f};
            #pragma unroll
            for (int t = 0; t < 2; ++t) {
                const int c = g*2 + t;
                #pragma unroll
                for (int s = 0; s < 2; ++s) {
                    short8 af = *(const short8*)&Ks[s*4096 + (c*16 + l16)*32 + swz];
                    #pragma unroll
                    for (int qg = 0; qg < 2; ++qg)
                        Sc[t][qg] = __builtin_amdgcn_mfma_f32_16x16x32_bf16(
                            af, qf[qg][s], Sc[t][qg], 0, 0, 0);
                }
            }
            // exp2 + pack directly into PV A-frags (registers only)
            short8 a8[2];
            #pragma unroll
            for (int qg = 0; qg < 2; ++qg) {
                float p[8];
                #pragma unroll
                for (int t = 0; t < 2; ++t)
                    #pragma unroll
                    for (int r = 0; r < 4; ++r) p[t*4+r] = exp2f(Sc[t][qg][r]);
                l_p[qg] += ((p[0]+p[1]) + (p[2]+p[3])) + ((p[4]+p[5]) + (p[6]+p[7]));
                unsigned int pk[4];
                #pragma unroll
                for (int e = 0; e < 4; ++e) {
                    __hip_bfloat162 w = __float22bfloat162_rn(make_float2(p[2*e], p[2*e+1]));
                    __builtin_memcpy(&pk[e], &w, 4);
                }
                __builtin_memcpy(&a8[qg], pk, 16);
            }
            // O += P @ V (slot-permuted key order on both sides)
            #pragma unroll
            for (int dt = 0; dt < 4; ++dt) {
                short8 bf = *(const short8*)&Vt[g*2048 + (dt*16 + l16)*32 + swz];
                #pragma unroll
                for (int qg = 0; qg < 2; ++qg)
                    Oacc[qg][dt] = __builtin_amdgcn_mfma_f32_16x16x32_bf16(
                        a8[qg], bf, Oacc[qg][dt], 0, 0, 0);
            }
        }
    }

    // l: reduce across quads (lane bits 4,5) -> full per-q sums in each lane
    #pragma unroll
    for (int qg = 0; qg < 2; ++qg) {
        l_p[qg] += __shfl_xor(l_p[qg], 16);
        l_p[qg] += __shfl_xor(l_p[qg], 32);
    }

    // partials: Opart[half][bh][qt][128 q][64 d] bf16; Lpart[half][bh][2048 q]
    size_t obase = (((size_t)((half*32 + bh)*16 + qt))*128)*64;
    #pragma unroll
    for (int qg = 0; qg < 2; ++qg) {
        #pragma unroll
        for (int r = 0; r < 4; ++r) {
            int ql = wave*32 + qg*16 + quad*4 + r;
            unsigned short* dst = Opart + obase + (size_t)ql*64;
            #pragma unroll
            for (int dt = 0; dt < 4; ++dt)
                dst[dt*16 + l16] = f2bf(Oacc[qg][dt][r]);
        }
        if (quad == 0)
            Lpart[((size_t)(half*32 + bh))*SEQ + qt*128 + wave*32 + qg*16 + l16]
                = l_p[qg];
    }
}

// ---------------------------------------------------------------------------
// Combine: ctxb[b,s,h*64+d] = (O1+O2)/(l1+l2). 512K threads, 8 d each.
// ---------------------------------------------------------------------------
__global__ __launch_bounds__(256) void attn_combine_kernel(
    const unsigned short* __restrict__ Opart, const float* __restrict__ Lpart,
    unsigned short* __restrict__ ctxb)
{
    const size_t HS = (size_t)32*16*128*64;  // half stride in ushorts (4 Mi)
    int idx = blockIdx.x*256 + threadIdx.x;  // [bh 32][q 2048][oct 8]
    int oct = idx & 7;
    int q   = (idx >> 3) & (SEQ-1);
    int bh  = idx >> 14;
    int qt = q >> 7, ql = q & 127;
    size_t pbase = ((((size_t)(bh*16 + qt))*128 + ql)*64) + oct*8;
    u16x8 o1 = *(const u16x8*)(Opart + pbase);
    u16x8 o2 = *(const u16x8*)(Opart + HS + pbase);
    float l = Lpart[(size_t)bh*SEQ + q] + Lpart[(size_t)32*SEQ + bh*SEQ + q];
    float inv = 1.0f / l;
    u16x8 o;
    #pragma unroll
    for (int e = 0; e < 8; ++e)
        o[e] = f2bf((bf2f(o1[e]) + bf2f(o2[e])) * inv);
    int b = bh >> 4, h = bh & 15;
    *(u16x8*)(ctxb + ((size_t)(b*SEQ + q))*DM + h*HD + oct*8) = o;
}

// ---------------------------------------------------------------------------
extern "C" void kernel_launch(void* const* d_in, const int* in_sizes, int n_in,
                              void* d_out, int out_size, void* d_ws, size_t ws_size,
                              hipStream_t stream) {
    const float* x  = (const float*)d_in[0];
    const float* Wq = (const float*)d_in[1];
    const float* bq = (const float*)d_in[2];
    const float* Wk = (const float*)d_in[3];
    const float* bk = (const float*)d_in[4];
    const float* Wv = (const float*)d_in[5];
    const float* bv = (const float*)d_in[6];
    const float* Wo = (const float*)d_in[7];
    const float* bo = (const float*)d_in[8];
    float* out = (float*)d_out;

    char* ws = (char*)d_ws;
    unsigned short* xb   = (unsigned short*)(ws);                    // 8 MB
    unsigned short* Wt   = (unsigned short*)(ws +  8u*1024*1024);    // 8 MB (4x2)
    unsigned short* qb   = (unsigned short*)(ws + 16u*1024*1024);    // 8 MB
    unsigned short* kb   = (unsigned short*)(ws + 24u*1024*1024);    // 8 MB
    unsigned short* vtg  = (unsigned short*)(ws + 32u*1024*1024);    // 8 MB (V^T)
    unsigned short* ctxb = (unsigned short*)(ws + 40u*1024*1024);    // 8 MB
    unsigned short* Op   = (unsigned short*)(ws + 48u*1024*1024);    // 16 MB partials
    float*          Lp   = (float*)(ws);   // 512 KB, overlays xb (dead post-qkv)

    cvt_xw_kernel<<<3072, 256, 0, stream>>>(x, xb, Wq, Wk, Wv, Wo, Wt);

    qkv_gemm_kernel<<<dim3(MTOT/128, DM/128, 3), 256, 0, stream>>>(
        xb, Wt, bq, bk, bv, qb, kb, vtg);

    attn_mfma_kernel<<<1024, 256, 0, stream>>>(qb, kb, vtg, Op, Lp);
    attn_combine_kernel<<<2048, 256, 0, stream>>>(Op, Lp, ctxb);

    out_gemm_kernel<<<dim3(MTOT/64, DM/128), 256, 0, stream>>>(
        ctxb, Wt + (size_t)3*DM*DM, bo, out);
    (void)in_sizes; (void)n_in; (void)out_size; (void)ws_size;
}

// Round 16
// 195.049 us; speedup vs baseline: 1.0622x; 1.0622x over previous
//
#include <hip/hip_runtime.h>
#include <hip/hip_bf16.h>
#include <math.h>

#define SEQ 2048
#define DM 1024
#define NH 16
#define HD 64
#define NBH 32      // B*NH
#define MTOT 4096   // B*SEQ

typedef __attribute__((ext_vector_type(8))) short short8;
typedef __attribute__((ext_vector_type(4))) float floatx4;
typedef __attribute__((ext_vector_type(8))) unsigned short u16x8;
typedef __attribute__((ext_vector_type(4))) unsigned short u16x4;

__device__ __forceinline__ unsigned short f2bf(float f) {
    unsigned int u = __float_as_uint(f);
    u += 0x7FFFu + ((u >> 16) & 1u);    // round-to-nearest-even
    return (unsigned short)(u >> 16);
}
__device__ __forceinline__ float bf2f(unsigned short h) {
    unsigned int u = (unsigned int)h << 16;
    return __uint_as_float(u);
}

#define AS1C const __attribute__((address_space(1))) void*
#define AS3  __attribute__((address_space(3))) void*

// 0.125 * log2(e): folds the 1/sqrt(64) score scale AND the exp->exp2
// conversion into Q's projection epilogue.
#define QSCALE 0.18033688011112042f

// ---------------------------------------------------------------------------
// Merged conversion kernel:
//  blocks [0,2048):    x fp32 [4096][1024] -> bf16 xb (8 elems/thread)
//  blocks [2048,3072): W fp32 [K][N] -> Wt bf16 [N][K], 64x64 tiles, 4 Ws
// ---------------------------------------------------------------------------
__global__ __launch_bounds__(256) void cvt_xw_kernel(
    const float* __restrict__ x, unsigned short* __restrict__ xb,
    const float* __restrict__ Wq, const float* __restrict__ Wk,
    const float* __restrict__ Wv, const float* __restrict__ Wo,
    unsigned short* __restrict__ Wt)
{
    if (blockIdx.x < 2048) {
        size_t base = ((size_t)blockIdx.x * 256 + threadIdx.x) * 8;
        float4 a = *(const float4*)(x + base);
        float4 b = *(const float4*)(x + base + 4);
        u16x8 o;
        o[0]=f2bf(a.x); o[1]=f2bf(a.y); o[2]=f2bf(a.z); o[3]=f2bf(a.w);
        o[4]=f2bf(b.x); o[5]=f2bf(b.y); o[6]=f2bf(b.z); o[7]=f2bf(b.w);
        *(u16x8*)(xb + base) = o;
        return;
    }
    __shared__ float Ls[64][65];
    const int bid = blockIdx.x - 2048;
    const int z = bid >> 8;
    const float* src = (z==0) ? Wq : (z==1) ? Wk : (z==2) ? Wv : Wo;
    unsigned short* dst = Wt + (size_t)z * DM * DM;
    const int tid = threadIdx.x;
    const int k0 = (bid & 15) * 64, n0 = ((bid >> 4) & 15) * 64;

    int r = tid >> 2, cseg = (tid & 3) * 16;
    #pragma unroll
    for (int e = 0; e < 4; ++e) {
        float4 v = *(const float4*)(src + (size_t)(k0 + r) * DM + n0 + cseg + e*4);
        Ls[r][cseg+e*4+0] = v.x; Ls[r][cseg+e*4+1] = v.y;
        Ls[r][cseg+e*4+2] = v.z; Ls[r][cseg+e*4+3] = v.w;
    }
    __syncthreads();
    int n = tid >> 2, kseg = (tid & 3) * 16;
    #pragma unroll
    for (int half = 0; half < 2; ++half) {
        u16x8 o;
        #pragma unroll
        for (int e = 0; e < 8; ++e) o[e] = f2bf(Ls[kseg + half*8 + e][n]);
        *(u16x8*)(dst + (size_t)(n0 + n) * DM + k0 + kseg + half*8) = o;
    }
}

// ---------------------------------------------------------------------------
// bf16 MFMA GEMM core (m97 structure, r9/r14-proven): C[128][128], BK=32.
// (r15's XOR swizzle reverted: neutral — GEMMs are drain-bound, not
// conflict-bound; conflicts hide under the barrier drains.)
// ---------------------------------------------------------------------------
#define GEMM_CORE(A_, Bt_, m0_, n0_)                                          \
    const int tid = threadIdx.x;                                              \
    const int wave = tid >> 6, lane = tid & 63;                               \
    const int quad = lane >> 4, l16 = lane & 15;                              \
    const int mh = (wave & 1) * 64, nh = (wave >> 1) * 64;                    \
    floatx4 acc[4][4];                                                        \
    _Pragma("unroll")                                                         \
    for (int i = 0; i < 4; ++i)                                               \
        _Pragma("unroll")                                                     \
        for (int j = 0; j < 4; ++j) acc[i][j] = (floatx4){0.f,0.f,0.f,0.f};   \
    {                                                                         \
        const int srow = wave*32 + (lane>>2);                                 \
        const int scol = (lane & 3) * 8;                                      \
        const unsigned short* ga = A_ + (size_t)(m0_ + srow)*DM + scol;       \
        const unsigned short* gb = Bt_ + (size_t)(n0_ + srow)*DM + scol;      \
        char* lA = (char*)As; char* lB = (char*)Bs;                           \
        for (int k0 = 0; k0 < DM; k0 += 32) {                                 \
            __syncthreads();                                                  \
            _Pragma("unroll")                                                 \
            for (int u = 0; u < 2; ++u) {                                     \
                __builtin_amdgcn_global_load_lds(                             \
                    (AS1C)(ga + (size_t)u*16*DM + k0),                        \
                    (AS3)(lA + (wave*32 + u*16)*64), 16, 0, 0);               \
                __builtin_amdgcn_global_load_lds(                             \
                    (AS1C)(gb + (size_t)u*16*DM + k0),                        \
                    (AS3)(lB + (wave*32 + u*16)*64), 16, 0, 0);               \
            }                                                                 \
            __syncthreads();                                                  \
            short8 af[4], bf[4];                                              \
            _Pragma("unroll")                                                 \
            for (int t = 0; t < 4; ++t) {                                     \
                af[t] = *(const short8*)&As[(mh + t*16 + l16)*32 + quad*8];   \
                bf[t] = *(const short8*)&Bs[(nh + t*16 + l16)*32 + quad*8];   \
            }                                                                 \
            _Pragma("unroll")                                                 \
            for (int mt = 0; mt < 4; ++mt)                                    \
                _Pragma("unroll")                                             \
                for (int nt = 0; nt < 4; ++nt)                                \
                    acc[mt][nt] = __builtin_amdgcn_mfma_f32_16x16x32_bf16(    \
                        af[mt], bf[nt], acc[mt][nt], 0, 0, 0);                \
        }                                                                     \
    }

// ---------------------------------------------------------------------------
// QKV projection GEMM (r9-proven). grid (32, 8, 3): z=0 q(rope+QSCALE),
// 1 k(rope), 2 v -> V^T to global, key axis slot-permuted per 32-key block
// (key 16t+4q+r at slot 8q+4t+r). Q/K in pi-permuted dh layout.
// ---------------------------------------------------------------------------
__global__ __launch_bounds__(256, 3) void qkv_gemm_kernel(
    const unsigned short* __restrict__ xb, const unsigned short* __restrict__ Wt,
    const float* __restrict__ bq, const float* __restrict__ bk,
    const float* __restrict__ bv,
    unsigned short* __restrict__ qb, unsigned short* __restrict__ kb,
    unsigned short* __restrict__ vtg)
{
    __shared__ unsigned short As[128*32];
    __shared__ unsigned short Bs[128*32];
    const int z = blockIdx.z;
    const unsigned short* Bt = Wt + (size_t)z * DM * DM;
    const float* bias = (z==0) ? bq : (z==1) ? bk : bv;
    const int m0 = blockIdx.x * 128, n0 = blockIdx.y * 128;

    GEMM_CORE(xb, Bt, m0, n0)

    float bb[4];
    #pragma unroll
    for (int nt = 0; nt < 4; ++nt) bb[nt] = bias[n0 + nh + nt*16 + l16];

    if (z == 2) {
        // V^T epilogue with slot permutation: 4 rounds of LDS transpose.
        unsigned short* Tw = (wave & 1) ? Bs : As;
        const int b = m0 >> 11;
        const int bufsel = tid >> 7, nl = tid & 127;
        const int ng = n0 + nl, hh = ng >> 6, dhh = ng & 63;
        unsigned short* vrow = vtg + ((size_t)((b*NH + hh)*HD + dhh))*SEQ;
        #pragma unroll
        for (int t = 0; t < 4; ++t) {
            __syncthreads();
            #pragma unroll
            for (int nt = 0; nt < 4; ++nt)
                #pragma unroll
                for (int r = 0; r < 4; ++r)
                    Tw[(nh + nt*16 + l16)*24 + quad*4 + r] =
                        f2bf(acc[t][nt][r] + bb[nt]);
            __syncthreads();
            const unsigned short* T2 = bufsel ? Bs : As;
            int sbase = (m0 & 2047) + bufsel*64 + t*16;   // 16-aligned
            int t32 = (sbase >> 4) & 1;
            int sb32 = sbase & ~31;
            #pragma unroll
            for (int gq = 0; gq < 4; ++gq) {
                u16x4 v4 = *(const u16x4*)&T2[nl*24 + gq*4];
                *(u16x4*)(vrow + sb32 + gq*8 + t32*4) = v4;
            }
        }
    } else {
        unsigned short* outh = (z==0) ? qb : kb;
        const float scl = (z == 0) ? QSCALE : 1.0f;
        const int h = (n0 + nh) >> 6;   // one head per n-half
        float inv0 = __expf(-(float)l16        * 0.28782313662425572f);
        float inv1 = __expf(-(float)(l16 + 16) * 0.28782313662425572f);
        #pragma unroll
        for (int mt = 0; mt < 4; ++mt)
            #pragma unroll
            for (int r = 0; r < 4; ++r) {
                int m = m0 + mh + mt*16 + quad*4 + r;
                int b = m >> 11, s = m & (SEQ-1);
                float s0, c0, s1, c1;
                __sincosf((float)s * inv0, &s0, &c0);
                __sincosf((float)s * inv1, &s1, &c1);
                float a0 = acc[mt][0][r] + bb[0];   // col l16
                float a1 = acc[mt][1][r] + bb[1];   // col l16+16
                float a2 = acc[mt][2][r] + bb[2];   // col l16+32
                float a3 = acc[mt][3][r] + bb[3];   // col l16+48
                u16x4 o;
                o[0] = f2bf((a0*c0 - a2*s0) * scl);
                o[1] = f2bf((a1*c1 - a3*s1) * scl);
                o[2] = f2bf((a2*c0 + a0*s0) * scl);
                o[3] = f2bf((a3*c1 + a1*s1) * scl);
                *(u16x4*)(outh + ((size_t)((b*NH + h)*SEQ + s))*HD + 4*l16) = o;
            }
    }
}

// ---------------------------------------------------------------------------
// Output GEMM v2: 64x128 tile, grid (64,8) = 2 blocks/CU. acc 4x2.
// ---------------------------------------------------------------------------
__global__ __launch_bounds__(256, 2) void out_gemm_kernel(
    const unsigned short* __restrict__ ctxb, const unsigned short* __restrict__ Wto,
    const float* __restrict__ bo, float* __restrict__ outf)
{
    __shared__ unsigned short As[64*32];    // 4 KB
    __shared__ unsigned short Bs[128*32];   // 8 KB
    const int tid = threadIdx.x;
    const int wave = tid >> 6, lane = tid & 63;
    const int quad = lane >> 4, l16 = lane & 15;
    const int m0 = blockIdx.x * 64, n0 = blockIdx.y * 128;
    const int nw = wave * 32;

    floatx4 acc[4][2];
    #pragma unroll
    for (int i = 0; i < 4; ++i)
        #pragma unroll
        for (int j = 0; j < 2; ++j) acc[i][j] = (floatx4){0.f,0.f,0.f,0.f};

    const int srow = lane >> 2;
    const int scol = (lane & 3) * 8;
    const unsigned short* ga = ctxb + (size_t)(m0 + wave*16 + srow)*DM + scol;
    const unsigned short* gb = Wto + (size_t)(n0 + wave*16 + srow)*DM + scol;
    char* lA = (char*)As; char* lB = (char*)Bs;

    for (int k0 = 0; k0 < DM; k0 += 32) {
        __syncthreads();
        __builtin_amdgcn_global_load_lds((AS1C)(ga + k0),
                                         (AS3)(lA + wave*1024), 16, 0, 0);
        #pragma unroll
        for (int u = 0; u < 2; ++u)
            __builtin_amdgcn_global_load_lds((AS1C)(gb + (size_t)u*64*DM + k0),
                                             (AS3)(lB + u*4096 + wave*1024), 16, 0, 0);
        __syncthreads();
        short8 af[4], bf[2];
        #pragma unroll
        for (int t = 0; t < 4; ++t)
            af[t] = *(const short8*)&As[(t*16 + l16)*32 + quad*8];
        #pragma unroll
        for (int t = 0; t < 2; ++t)
            bf[t] = *(const short8*)&Bs[(nw + t*16 + l16)*32 + quad*8];
        #pragma unroll
        for (int mt = 0; mt < 4; ++mt)
            #pragma unroll
            for (int nt = 0; nt < 2; ++nt)
                acc[mt][nt] = __builtin_amdgcn_mfma_f32_16x16x32_bf16(
                    af[mt], bf[nt], acc[mt][nt], 0, 0, 0);
    }

    float bb[2];
    #pragma unroll
    for (int nt = 0; nt < 2; ++nt) bb[nt] = bo[n0 + nw + nt*16 + l16];
    #pragma unroll
    for (int mt = 0; mt < 4; ++mt)
        #pragma unroll
        for (int r = 0; r < 4; ++r) {
            int m = m0 + mt*16 + quad*4 + r;
            #pragma unroll
            for (int nt = 0; nt < 2; ++nt)
                outf[(size_t)m*DM + n0 + nw + nt*16 + l16] = acc[mt][nt][r] + bb[nt];
        }
}

// ---------------------------------------------------------------------------
// Flash attention v6 + raw-exp: identical to r14 (58.8 us) except exp2f ->
// __builtin_amdgcn_exp2f. Theory: libm exp2f (no -ffast-math) expands to
// __ocml_exp2_f32 = v_exp_f32 + ~6-10 fixup instrs; 64 exps/wave-iter made
// that the hidden bulk of VALUBusy=57%. Raw v_exp_f32 is exact enough here
// (|s'| <~ 30, no denormal contributions, no NaN/Inf inputs).
// ---------------------------------------------------------------------------
__global__ __launch_bounds__(256, 2) void attn_mfma_kernel(
    const unsigned short* __restrict__ Q, const unsigned short* __restrict__ K,
    const unsigned short* __restrict__ Vtg,
    unsigned short* __restrict__ Opart, float* __restrict__ Lpart)
{
    __shared__ unsigned short Ks[2*128*32];   // 16 KB [d-half][key][32]
    __shared__ unsigned short Vt[4*64*32];    // 16 KB [key-group][d][32 slots]

    const int tid  = threadIdx.x;
    const int wave = tid >> 6, lane = tid & 63;
    const int quad = lane >> 4, l16 = lane & 15;
    const int bh   = blockIdx.x & 31;            // XCD-local
    const int qt   = (blockIdx.x >> 5) & 15;     // q-tile (128 rows)
    const int half = blockIdx.x >> 9;            // key half

    const unsigned short* Qb = Q + (size_t)bh * SEQ * HD;
    const unsigned short* Kb = K + (size_t)bh * SEQ * HD + (size_t)half*1024*HD;
    const unsigned short* Vb = Vtg + (size_t)bh * HD * SEQ + half*1024;

    // Q fragments in registers: qf[qg][s] = Q[q = wave*32+qg*16+l16][d s-half]
    short8 qf[2][2];
    #pragma unroll
    for (int qg = 0; qg < 2; ++qg) {
        const unsigned short* qrow =
            Qb + (size_t)(qt*128 + wave*32 + qg*16 + l16)*HD;
        qf[qg][0] = *(const short8*)(qrow + quad*8);
        qf[qg][1] = *(const short8*)(qrow + 32 + quad*8);
    }

    // DMA staging: waves 0-1 stage K (16KB), waves 2-3 stage V (16KB);
    // 8 issues x 16B/thread. Granule XOR on (row>>2)&3.
    const unsigned short* gsrc[8];
    char* ldst[8];
    int step;
    if (wave < 2) {
        #pragma unroll
        for (int u = 0; u < 8; ++u) {
            int G = u*128 + wave*64 + lane;      // granule 0..1023
            int gl = G & 3, key = (G >> 2) & 127, s = G >> 9;
            gsrc[u] = Kb + (size_t)key*HD + s*32 + (gl ^ ((key>>2)&3))*8;
            ldst[u] = (char*)Ks + G*16;
        }
        step = 128*HD;
    } else {
        #pragma unroll
        for (int u = 0; u < 8; ++u) {
            int G = u*128 + (wave-2)*64 + lane;
            int gl = G & 3, d = (G >> 2) & 63, g = G >> 8;
            gsrc[u] = Vb + (size_t)d*SEQ + g*32 + (gl ^ ((d>>2)&3))*8;
            ldst[u] = (char*)Vt + G*16;
        }
        step = 128;
    }

    float l_p[2] = {0.f, 0.f};
    floatx4 Oacc[2][4];
    #pragma unroll
    for (int qg = 0; qg < 2; ++qg)
        #pragma unroll
        for (int dt = 0; dt < 4; ++dt) Oacc[qg][dt] = (floatx4){0.f,0.f,0.f,0.f};

    const int swz = (quad ^ (l16 >> 2)) * 8;

    for (int kt = 0; kt < 8; ++kt) {
        __syncthreads();   // prev iter done reading Ks/Vt
        #pragma unroll
        for (int u = 0; u < 8; ++u)
            __builtin_amdgcn_global_load_lds((AS1C)gsrc[u], (AS3)ldst[u], 16, 0, 0);
        #pragma unroll
        for (int u = 0; u < 8; ++u) gsrc[u] += step;
        __syncthreads();   // DMA drained

        #pragma unroll
        for (int g = 0; g < 4; ++g) {            // 32-key groups
            // S^T = K @ Q^T for the group's two 16-key tiles
            floatx4 Sc[2][2];                    // [t][qg]
            #pragma unroll
            for (int t = 0; t < 2; ++t)
                #pragma unroll
                for (int qg = 0; qg < 2; ++qg) Sc[t][qg] = (floatx4){0.f,0.f,0.f,0.f};
            #pragma unroll
            for (int t = 0; t < 2; ++t) {
                const int c = g*2 + t;
                #pragma unroll
                for (int s = 0; s < 2; ++s) {
                    short8 af = *(const short8*)&Ks[s*4096 + (c*16 + l16)*32 + swz];
                    #pragma unroll
                    for (int qg = 0; qg < 2; ++qg)
                        Sc[t][qg] = __builtin_amdgcn_mfma_f32_16x16x32_bf16(
                            af, qf[qg][s], Sc[t][qg], 0, 0, 0);
                }
            }
            // exp2 (raw v_exp_f32) + pack directly into PV A-frags
            short8 a8[2];
            #pragma unroll
            for (int qg = 0; qg < 2; ++qg) {
                float p[8];
                #pragma unroll
                for (int t = 0; t < 2; ++t)
                    #pragma unroll
                    for (int r = 0; r < 4; ++r)
                        p[t*4+r] = __builtin_amdgcn_exp2f(Sc[t][qg][r]);
                l_p[qg] += ((p[0]+p[1]) + (p[2]+p[3])) + ((p[4]+p[5]) + (p[6]+p[7]));
                unsigned int pk[4];
                #pragma unroll
                for (int e = 0; e < 4; ++e) {
                    __hip_bfloat162 w = __float22bfloat162_rn(make_float2(p[2*e], p[2*e+1]));
                    __builtin_memcpy(&pk[e], &w, 4);
                }
                __builtin_memcpy(&a8[qg], pk, 16);
            }
            // O += P @ V (slot-permuted key order on both sides)
            #pragma unroll
            for (int dt = 0; dt < 4; ++dt) {
                short8 bf = *(const short8*)&Vt[g*2048 + (dt*16 + l16)*32 + swz];
                #pragma unroll
                for (int qg = 0; qg < 2; ++qg)
                    Oacc[qg][dt] = __builtin_amdgcn_mfma_f32_16x16x32_bf16(
                        a8[qg], bf, Oacc[qg][dt], 0, 0, 0);
            }
        }
    }

    // l: reduce across quads (lane bits 4,5) -> full per-q sums in each lane
    #pragma unroll
    for (int qg = 0; qg < 2; ++qg) {
        l_p[qg] += __shfl_xor(l_p[qg], 16);
        l_p[qg] += __shfl_xor(l_p[qg], 32);
    }

    // partials: Opart[half][bh][qt][128 q][64 d] bf16; Lpart[half][bh][2048 q]
    size_t obase = (((size_t)((half*32 + bh)*16 + qt))*128)*64;
    #pragma unroll
    for (int qg = 0; qg < 2; ++qg) {
        #pragma unroll
        for (int r = 0; r < 4; ++r) {
            int ql = wave*32 + qg*16 + quad*4 + r;
            unsigned short* dst = Opart + obase + (size_t)ql*64;
            #pragma unroll
            for (int dt = 0; dt < 4; ++dt)
                dst[dt*16 + l16] = f2bf(Oacc[qg][dt][r]);
        }
        if (quad == 0)
            Lpart[((size_t)(half*32 + bh))*SEQ + qt*128 + wave*32 + qg*16 + l16]
                = l_p[qg];
    }
}

// ---------------------------------------------------------------------------
// Combine: ctxb[b,s,h*64+d] = (O1+O2)/(l1+l2). 512K threads, 8 d each.
// ---------------------------------------------------------------------------
__global__ __launch_bounds__(256) void attn_combine_kernel(
    const unsigned short* __restrict__ Opart, const float* __restrict__ Lpart,
    unsigned short* __restrict__ ctxb)
{
    const size_t HS = (size_t)32*16*128*64;  // half stride in ushorts (4 Mi)
    int idx = blockIdx.x*256 + threadIdx.x;  // [bh 32][q 2048][oct 8]
    int oct = idx & 7;
    int q   = (idx >> 3) & (SEQ-1);
    int bh  = idx >> 14;
    int qt = q >> 7, ql = q & 127;
    size_t pbase = ((((size_t)(bh*16 + qt))*128 + ql)*64) + oct*8;
    u16x8 o1 = *(const u16x8*)(Opart + pbase);
    u16x8 o2 = *(const u16x8*)(Opart + HS + pbase);
    float l = Lpart[(size_t)bh*SEQ + q] + Lpart[(size_t)32*SEQ + bh*SEQ + q];
    float inv = 1.0f / l;
    u16x8 o;
    #pragma unroll
    for (int e = 0; e < 8; ++e)
        o[e] = f2bf((bf2f(o1[e]) + bf2f(o2[e])) * inv);
    int b = bh >> 4, h = bh & 15;
    *(u16x8*)(ctxb + ((size_t)(b*SEQ + q))*DM + h*HD + oct*8) = o;
}

// ---------------------------------------------------------------------------
extern "C" void kernel_launch(void* const* d_in, const int* in_sizes, int n_in,
                              void* d_out, int out_size, void* d_ws, size_t ws_size,
                              hipStream_t stream) {
    const float* x  = (const float*)d_in[0];
    const float* Wq = (const float*)d_in[1];
    const float* bq = (const float*)d_in[2];
    const float* Wk = (const float*)d_in[3];
    const float* bk = (const float*)d_in[4];
    const float* Wv = (const float*)d_in[5];
    const float* bv = (const float*)d_in[6];
    const float* Wo = (const float*)d_in[7];
    const float* bo = (const float*)d_in[8];
    float* out = (float*)d_out;

    char* ws = (char*)d_ws;
    unsigned short* xb   = (unsigned short*)(ws);                    // 8 MB
    unsigned short* Wt   = (unsigned short*)(ws +  8u*1024*1024);    // 8 MB (4x2)
    unsigned short* qb   = (unsigned short*)(ws + 16u*1024*1024);    // 8 MB
    unsigned short* kb   = (unsigned short*)(ws + 24u*1024*1024);    // 8 MB
    unsigned short* vtg  = (unsigned short*)(ws + 32u*1024*1024);    // 8 MB (V^T)
    unsigned short* ctxb = (unsigned short*)(ws + 40u*1024*1024);    // 8 MB
    unsigned short* Op   = (unsigned short*)(ws + 48u*1024*1024);    // 16 MB partials
    float*          Lp   = (float*)(ws);   // 512 KB, overlays xb (dead post-qkv)

    cvt_xw_kernel<<<3072, 256, 0, stream>>>(x, xb, Wq, Wk, Wv, Wo, Wt);

    qkv_gemm_kernel<<<dim3(MTOT/128, DM/128, 3), 256, 0, stream>>>(
        xb, Wt, bq, bk, bv, qb, kb, vtg);

    attn_mfma_kernel<<<1024, 256, 0, stream>>>(qb, kb, vtg, Op, Lp);
    attn_combine_kernel<<<2048, 256, 0, stream>>>(Op, Lp, ctxb);

    out_gemm_kernel<<<dim3(MTOT/64, DM/128), 256, 0, stream>>>(
        ctxb, Wt + (size_t)3*DM*DM, bo, out);
    (void)in_sizes; (void)n_in; (void)out_size; (void)ws_size;
}